// Round 5
// baseline (308.778 us; speedup 1.0000x reference)
//
#include <hip/hip_runtime.h>
#include <hip/hip_bf16.h>

// Problem constants (B,S,D,H = 2,2048,2048,16 ; DPH = 128)
#define BB 2
#define HH 16
#define SS 2048
#define DD 2048
#define DPH_ 128
#define QBLK 64
#define KBLK 64
#define NT (SS / KBLK)   // 32

// LDS strides (bf16 elements); row strides must be 16B multiples for b128
#define KSTR 136   // kls [64 kv][KSTR]  272B = 17*16  ✓
#define VSTR 72    // vls [128 dph][VSTR] 144B = 9*16  ✓

typedef __bf16 bf16x8 __attribute__((ext_vector_type(8)));
typedef float f32x4 __attribute__((ext_vector_type(4)));
typedef float f32x16 __attribute__((ext_vector_type(16)));
typedef unsigned int u32x4 __attribute__((ext_vector_type(4)));

__device__ __forceinline__ unsigned f2bfbits(float f) {
  unsigned u = __builtin_bit_cast(unsigned, f);
  u += 0x7FFFu + ((u >> 16) & 1u);   // RNE
  return u >> 16;
}

// Swapped-operand fused flash attention. 4 waves = 2 qgrp x 2 kv-half.
// Per wave: S^T tile [32kv x 32q] (kv lane-local -> in-register softmax),
// partial O^T [128d x 32q] over its kv-half, epilogue split-kv merge.
// Also emits: raw scores (dot), prev_key/prev_value (exact fp32), mask.
// Register budget note: peak live ~143 VGPR (o16 64 + qB 16 + s 16 + f 32
// + addr) -> fits the 168 cap from (256,3) WITHOUT in-loop spills, which is
// the round-4 regression cause being fixed here.
__global__ __launch_bounds__(256, 3)
void attn_fused(const float* __restrict__ q, const int* __restrict__ maski,
                float* __restrict__ out, float* __restrict__ dot,
                float* __restrict__ pk, float* __restrict__ pv,
                float* __restrict__ omask) {
  __shared__ __align__(16) char smem[35840];   // kls+vls; reused as merge buf
  __shared__ float st[2][2][32][2];            // [qgrp][kvh][q][{m,l}]
  __bf16* kls = (__bf16*)smem;                 // [64][KSTR]   17408 B
  __bf16* vls = kls + KBLK * KSTR;             // [128][VSTR]  18432 B
  float* mrg = (float*)smem;                   // epilogue: [2][128d][32q] 32KB

  // XCD-bijective swizzle: 1024 blocks = 8 xcd x (32 qt x 4 (b,h)-groups)
  const int bid = blockIdx.x;
  const int xcd = bid & 7;
  const int idx = bid >> 3;          // 0..127
  const int qt  = idx & 31;
  const int G   = (idx >> 5) * 8 + xcd;  // 0..31 = b*16+h
  const int h   = G & 15;
  const int b   = G >> 4;

  const int tid  = threadIdx.x;
  const int wid  = tid >> 6;
  const int qgrp = wid & 1;          // 32-q group
  const int kvh  = wid >> 1;         // kv half (0..1)
  const int lane = tid & 63;
  const int c    = lane & 31;
  const int hl   = lane >> 5;

  // mask passthrough (block 0 only; disjoint from other outputs)
  if (bid == 0) {
    #pragma unroll
    for (int i = 0; i < 16; ++i)
      omask[tid + 256 * i] = (float)maski[tid + 256 * i];
  }

  const int qbase = qt * QBLK;
  const int qrow  = qbase + qgrp * 32 + c;
  const float scale = 0.08838834764831845f;   // 1/sqrt(128)
  const float* __restrict__ qh = q + (size_t)b * SS * DD + (size_t)h * DPH_;

  // ---- Q B-fragments in registers (col q = qrow, k = ks*16 + 8*hl + e) ----
  bf16x8 qB[8];
  {
    const float* qp = qh + (size_t)qrow * DD + 8 * hl;
    #pragma unroll
    for (int ks = 0; ks < 8; ++ks) {
      float4 a0 = *(const float4*)(qp + ks * 16);
      float4 a1 = *(const float4*)(qp + ks * 16 + 4);
      u32x4 t;
      t[0] = f2bfbits(a0.x) | (f2bfbits(a0.y) << 16);
      t[1] = f2bfbits(a0.z) | (f2bfbits(a0.w) << 16);
      t[2] = f2bfbits(a1.x) | (f2bfbits(a1.y) << 16);
      t[3] = f2bfbits(a1.z) | (f2bfbits(a1.w) << 16);
      qB[ks] = __builtin_bit_cast(bf16x8, t);
    }
  }

  // ---- staging ownership: row pair (2p2, 2p2+1), dph 16-chunk oo ----
  const int p2 = tid & 31;
  const int oo = tid >> 5;           // 0..7
  const int r0 = 2 * p2, r1 = r0 + 1;

  float4 f[8];                       // staged fp32 (rows r0:f[0..3], r1:f[4..7])
  unsigned kq[16];                   // bf16-packed (row-major)

  auto load_f = [&](int kvb) {
    const float* pA = qh + (size_t)(kvb + r0) * DD + 16 * oo;
    const float* pB = qh + (size_t)(kvb + r1) * DD + 16 * oo;
    #pragma unroll
    for (int i = 0; i < 4; ++i) {
      f[i]     = *(const float4*)(pA + 4 * i);
      f[4 + i] = *(const float4*)(pB + 4 * i);
    }
  };
  auto pkpv_store = [&](int kvb) {   // exact fp32 copies, [B,H,S,DPH]
    const size_t bh = (size_t)(b * HH + h);
    float* k0 = pk + (bh * SS + kvb + r0) * DPH_ + 16 * oo;
    float* k1 = pk + (bh * SS + kvb + r1) * DPH_ + 16 * oo;
    float* v0 = pv + (bh * SS + kvb + r0) * DPH_ + 16 * oo;
    float* v1 = pv + (bh * SS + kvb + r1) * DPH_ + 16 * oo;
    #pragma unroll
    for (int i = 0; i < 4; ++i) {
      *(float4*)(k0 + 4 * i) = f[i];   *(float4*)(k1 + 4 * i) = f[4 + i];
      *(float4*)(v0 + 4 * i) = f[i];   *(float4*)(v1 + 4 * i) = f[4 + i];
    }
  };
  auto convert_f = [&]() {           // f (32 regs) dies here -> kq (16 regs)
    #pragma unroll
    for (int i = 0; i < 4; ++i) {
      kq[2*i]     = f2bfbits(f[i].x)     | (f2bfbits(f[i].y) << 16);
      kq[2*i+1]   = f2bfbits(f[i].z)     | (f2bfbits(f[i].w) << 16);
      kq[8+2*i]   = f2bfbits(f[4+i].x)   | (f2bfbits(f[4+i].y) << 16);
      kq[8+2*i+1] = f2bfbits(f[4+i].z)   | (f2bfbits(f[4+i].w) << 16);
    }
  };
  auto write_kv = [&]() {
    u32x4 w0 = {kq[0], kq[1], kq[2],  kq[3]};
    u32x4 w1 = {kq[4], kq[5], kq[6],  kq[7]};
    u32x4 w2 = {kq[8], kq[9], kq[10], kq[11]};
    u32x4 w3 = {kq[12], kq[13], kq[14], kq[15]};
    *(u32x4*)(&kls[r0 * KSTR + 16 * oo])     = w0;
    *(u32x4*)(&kls[r0 * KSTR + 16 * oo + 8]) = w1;
    *(u32x4*)(&kls[r1 * KSTR + 16 * oo])     = w2;
    *(u32x4*)(&kls[r1 * KSTR + 16 * oo + 8]) = w3;
    // V^T: packed kv-pair b32 writes, conflict-free (bank = 4j + p2)
    #pragma unroll
    for (int j = 0; j < 16; ++j) {
      unsigned aA = (kq[j >> 1]       >> (16 * (j & 1))) & 0xFFFFu;
      unsigned aB = (kq[8 + (j >> 1)] >> (16 * (j & 1))) & 0xFFFFu;
      *(unsigned*)(&vls[(16 * oo + j) * VSTR + r0]) = aA | (aB << 16);
    }
  };

  f32x16 o16[4];
  #pragma unroll
  for (int dt = 0; dt < 4; ++dt)
    #pragma unroll
    for (int j = 0; j < 16; ++j) o16[dt][j] = 0.0f;
  float m = -1e30f, lsum = 0.0f;

  float* __restrict__ dotb = dot + ((size_t)(b * HH + h) << 22);  // S*S = 2^22

  // ---- prologue: stage tile 0 ----
  load_f(0);
  if (qt == 0) pkpv_store(0);
  convert_f();
  write_kv();
  __syncthreads();

  for (int kt = 0; kt < NT; ++kt) {
    const int kvbase = kt * KBLK;
    const int nxt = kvbase + KBLK;
    if (kt + 1 < NT) load_f(nxt);    // in flight under QK MFMAs

    // ---- QK^T swapped: S^T[kv][q], 8 MFMA 32x32x16 ----
    f32x16 s;
    #pragma unroll
    for (int j = 0; j < 16; ++j) s[j] = 0.0f;
    __builtin_amdgcn_s_setprio(1);
    #pragma unroll
    for (int ks = 0; ks < 8; ++ks) {
      bf16x8 kf = *(const bf16x8*)(&kls[(kvh * 32 + c) * KSTR + ks * 16 + 8 * hl]);
      s = __builtin_amdgcn_mfma_f32_32x32x16_bf16(kf, qB[ks], s, 0, 0, 0);
    }
    __builtin_amdgcn_s_setprio(0);
    s *= scale;

    // ---- retire fp32 staging regs EARLY (peak-pressure fix) ----
    if (kt + 1 < NT) {
      if (kt + 1 == qt) pkpv_store(nxt);  // exact fp32 before conversion
      convert_f();                        // f -> kq, f dies
    }

    // ---- raw scores -> dot[q][kv], f32x4 stores (L2 merges partial lines) --
    {
      float* dpb = dotb + (size_t)qrow * SS + kvbase + kvh * 32 + 4 * hl;
      #pragma unroll
      for (int rg = 0; rg < 4; ++rg) {
        f32x4 v = {s[4*rg], s[4*rg+1], s[4*rg+2], s[4*rg+3]};
        *(f32x4*)(dpb + 8 * rg) = v;
      }
    }

    // ---- online softmax, kv lane-local (T13 defer-max, THR=8) ----
    float mx = s[0];
    #pragma unroll
    for (int j = 1; j < 16; ++j) mx = fmaxf(mx, s[j]);
    mx = fmaxf(mx, __shfl_xor(mx, 32));
    if (!__all(mx - m <= 8.0f)) {
      float mn = fmaxf(m, mx);
      float al = __expf(m - mn);
      lsum *= al;
      #pragma unroll
      for (int dt = 0; dt < 4; ++dt) o16[dt] *= al;
      m = mn;
    }
    // exp -> pack fused: p values die into X immediately (no p[16] array)
    unsigned X[8];
    float sum = 0.0f;
    #pragma unroll
    for (int i = 0; i < 8; ++i) {
      float pa = __expf(s[2*i]   - m);
      float pb = __expf(s[2*i+1] - m);
      sum += pa + pb;
      X[i] = f2bfbits(pa) | (f2bfbits(pb) << 16);
    }
    sum += __shfl_xor(sum, 32);
    lsum += sum;

    // ---- P -> bf16 B-frags in-register (half-wave exchange) ----
    bf16x8 pf[2];
    #pragma unroll
    for (int ks = 0; ks < 2; ++ks) {
      unsigned XA = X[4*ks], XB = X[4*ks+1], XC = X[4*ks+2], XD = X[4*ks+3];
      unsigned sA = __shfl_xor(XA, 32), sB = __shfl_xor(XB, 32);
      unsigned sC = __shfl_xor(XC, 32), sD = __shfl_xor(XD, 32);
      u32x4 dd;
      dd[0] = hl ? sC : XA;
      dd[1] = hl ? sD : XB;
      dd[2] = hl ? XC : sA;
      dd[3] = hl ? XD : sB;
      pf[ks] = __builtin_bit_cast(bf16x8, dd);
    }

    // ---- PV: O^T += V^T * P^T over this wave's kv-half (8 MFMA) ----
    __builtin_amdgcn_s_setprio(1);
    #pragma unroll
    for (int ks = 0; ks < 2; ++ks) {
      #pragma unroll
      for (int dt = 0; dt < 4; ++dt) {
        bf16x8 vf = *(const bf16x8*)(&vls[(dt * 32 + c) * VSTR + kvh * 32 + ks * 16 + 8 * hl]);
        o16[dt] = __builtin_amdgcn_mfma_f32_32x32x16_bf16(vf, pf[ks], o16[dt], 0, 0, 0);
      }
    }
    __builtin_amdgcn_s_setprio(0);

    __syncthreads();                     // all waves done reading kls/vls
    if (kt + 1 < NT) write_kv();         // stage tile kt+1
    __syncthreads();
  }

  // ---- epilogue: split-kv merge across wave pairs, then store out ----
  if (hl == 0) { st[qgrp][kvh][c][0] = m; st[qgrp][kvh][c][1] = lsum; }
  __syncthreads();
  const float pm = st[qgrp][kvh ^ 1][c][0];
  const float pl = st[qgrp][kvh ^ 1][c][1];
  const float M  = fmaxf(m, pm);
  const float w  = __expf(m - M);
  const float wp = __expf(pm - M);

  if (kvh == 1) {
    #pragma unroll
    for (int dt = 0; dt < 4; ++dt)
      #pragma unroll
      for (int r = 0; r < 16; ++r) {
        int d = dt * 32 + (r & 3) + 8 * (r >> 2) + 4 * hl;
        mrg[qgrp * 4096 + d * 32 + c] = o16[dt][r] * w;
      }
  }
  __syncthreads();
  if (kvh == 0) {
    const float L = lsum * w + pl * wp;
    const float invL = 1.0f / L;
    float* ob = out + ((size_t)b * SS + qrow) * DD + h * DPH_;
    #pragma unroll
    for (int dt = 0; dt < 4; ++dt)
      #pragma unroll
      for (int rg = 0; rg < 4; ++rg) {
        f32x4 v;
        #pragma unroll
        for (int j = 0; j < 4; ++j) {
          int d = dt * 32 + j + 8 * rg + 4 * hl;
          v[j] = (o16[dt][4*rg + j] * w + mrg[qgrp * 4096 + d * 32 + c]) * invL;
        }
        *(f32x4*)(ob + dt * 32 + 8 * rg + 4 * hl) = v;
      }
  }
}

extern "C" void kernel_launch(void* const* d_in, const int* in_sizes, int n_in,
                              void* d_out, int out_size, void* d_ws, size_t ws_size,
                              hipStream_t stream) {
  const float* q    = (const float*)d_in[0];
  const int*   mask = (const int*)d_in[1];
  float* out = (float*)d_out;

  // Output layout (concatenated flat, fp32):
  float* o_out  = out;                 // [B,S,D]        8,388,608
  float* o_pk   = out + 8388608;       // [B,H,S,DPH]    8,388,608
  float* o_pv   = out + 16777216;      // [B,H,S,DPH]    8,388,608
  float* o_mask = out + 25165824;      // [B,S]              4,096
  float* o_dot  = out + 25169920;      // [B*H,S,S]    134,217,728

  // 1024 blocks = 32 qt x 16 h x 2 b, XCD-swizzled in-kernel
  attn_fused<<<dim3(1024), dim3(256), 0, stream>>>(
      q, mask, o_out, o_dot, o_pk, o_pv, o_mask);
}

// Round 6
// 194.547 us; speedup vs baseline: 1.5872x; 1.5872x over previous
//
#include <hip/hip_runtime.h>
#include <hip/hip_bf16.h>

// Problem constants (B,S,D,H = 2,2048,2048,16 ; DPH = 128)
#define BB 2
#define HH 16
#define SS 2048
#define DD 2048
#define DPH_ 128
#define QBLK 128
#define KBLK 64
#define NT (SS / KBLK)   // 32

// LDS strides (bf16 elements)
#define KSTR 136   // K-LDS  [KBLK][KSTR]  (kv-major, dph contiguous)
#define VSTR 72    // Vt-LDS [DPH][VSTR]   (dph-major, kv contiguous)
#define PSTR 72    // P-LDS  per-wave [16][PSTR]

typedef __bf16 bf16x8 __attribute__((ext_vector_type(8)));
typedef unsigned short u16x8 __attribute__((ext_vector_type(8)));
typedef float f32x4 __attribute__((ext_vector_type(4)));   // native vector (nontemporal-ok)

__device__ __forceinline__ unsigned short f2bfbits(float f) {
  unsigned u = __builtin_bit_cast(unsigned, f);
  u += 0x7FFFu + ((u >> 16) & 1u);   // RNE
  return (unsigned short)(u >> 16);
}
__device__ __forceinline__ __bf16 f2bf(float f) {
  unsigned short s = f2bfbits(f);
  return __builtin_bit_cast(__bf16, s);
}
__device__ __forceinline__ void nt_store4(const float4& v, float* p) {
  f32x4 t = {v.x, v.y, v.z, v.w};
  __builtin_nontemporal_store(t, (f32x4*)p);
}

// Slim preprocessor: q fp32 -> qb bf16 (scratch) + mask passthrough.
// (pk/pv copies are folded into the attention kernel's epilogue.)
template <bool PRE>
__global__ __launch_bounds__(256)
void preproc(const float* __restrict__ q, const int* __restrict__ mask,
             __bf16* __restrict__ qb, float* __restrict__ omask) {
  const size_t i = (size_t)blockIdx.x * 256 + threadIdx.x;  // 1,048,576 total
  const size_t e = i * 8;
  if constexpr (PRE) {
    const float4 v0 = *(const float4*)(q + e);
    const float4 v1 = *(const float4*)(q + e + 4);
    u16x8 t;
    t[0] = f2bfbits(v0.x); t[1] = f2bfbits(v0.y);
    t[2] = f2bfbits(v0.z); t[3] = f2bfbits(v0.w);
    t[4] = f2bfbits(v1.x); t[5] = f2bfbits(v1.y);
    t[6] = f2bfbits(v1.z); t[7] = f2bfbits(v1.w);
    *(u16x8*)(qb + e) = t;
  }
  if (i < (size_t)BB * SS) omask[i] = (float)mask[i];
}

// Fused flash attention, 8 waves x 16 Q-rows = 128 Q-rows per block.
// Writes raw scaled scores to dot_prod as a side effect of the online pass;
// epilogue also emits out and the exact-fp32 prev_key/prev_value copies.
template <bool PRE>
__global__ __launch_bounds__(512, 4)
void attn_fused(const __bf16* __restrict__ qb, const float* __restrict__ qf,
                float* __restrict__ out, float* __restrict__ dot,
                float* __restrict__ pk, float* __restrict__ pv) {
  __shared__ __bf16 kls[KBLK * KSTR];      // 17408 B
  __shared__ __bf16 vls[DPH_ * VSTR];      // 18432 B
  __shared__ __bf16 pls[8 * 16 * PSTR];    // 18432 B   total 54272 B

  // XCD-bijective swizzle: all 16 qt-blocks of one (b,h) land on one XCD.
  const int bid = blockIdx.x;
  const int xcd = bid & 7;
  const int t_  = bid >> 3;          // 0..63
  const int qt  = t_ & 15;
  const int G   = (t_ >> 4) * 8 + xcd;
  const int h   = G & 15;
  const int b   = G >> 4;

  const int tid  = threadIdx.x;
  const int wid  = tid >> 6;
  const int lane = tid & 63;
  const int g    = lane >> 4;   // 0..3
  const int c    = lane & 15;   // 0..15
  const int skv  = lane;        // staging kv row (== tid & 63)

  const int qbase = qt * QBLK;
  const float scale = 0.08838834764831845f;  // 1/sqrt(128)

  const size_t headoff = (size_t)b * SS * DD + (size_t)h * DPH_;
  const __bf16* qbh = PRE ? qb + headoff : nullptr;
  const float*  qfh = qf + headoff;

  // Q fragments: A-layout row = c (within wave's 16 rows), k = st*32+8g+i.
  bf16x8 aq[4];
  {
    const int row = qbase + wid * 16 + c;
    if constexpr (PRE) {
      const __bf16* p = qbh + (size_t)row * DD + 8 * g;
      #pragma unroll
      for (int st = 0; st < 4; ++st) aq[st] = *(const bf16x8*)(p + st * 32);
    } else {
      const float* p = qfh + (size_t)row * DD + 8 * g;
      #pragma unroll
      for (int st = 0; st < 4; ++st) {
        u16x8 t;
        #pragma unroll
        for (int i2 = 0; i2 < 8; ++i2) t[i2] = f2bfbits(p[st * 32 + i2]);
        aq[st] = __builtin_bit_cast(bf16x8, t);
      }
    }
  }

  // Tile staging: each thread owns row skv, octets wid and wid+8 (16B each).
  // Same registers feed both the kv-major K tile and the transposed V tile.
  auto load_tile = [&](int kvb, bf16x8& a0, bf16x8& a1) {
    if constexpr (PRE) {
      const __bf16* p = qbh + (size_t)(kvb + skv) * DD + wid * 8;
      a0 = *(const bf16x8*)p;
      a1 = *(const bf16x8*)(p + 64);
    } else {
      const float* p = qfh + (size_t)(kvb + skv) * DD + wid * 8;
      const float4 f0 = *(const float4*)p;
      const float4 f1 = *(const float4*)(p + 4);
      const float4 f2 = *(const float4*)(p + 64);
      const float4 f3 = *(const float4*)(p + 68);
      u16x8 t0, t1;
      t0[0] = f2bfbits(f0.x); t0[1] = f2bfbits(f0.y);
      t0[2] = f2bfbits(f0.z); t0[3] = f2bfbits(f0.w);
      t0[4] = f2bfbits(f1.x); t0[5] = f2bfbits(f1.y);
      t0[6] = f2bfbits(f1.z); t0[7] = f2bfbits(f1.w);
      t1[0] = f2bfbits(f2.x); t1[1] = f2bfbits(f2.y);
      t1[2] = f2bfbits(f2.z); t1[3] = f2bfbits(f2.w);
      t1[4] = f2bfbits(f3.x); t1[5] = f2bfbits(f3.y);
      t1[6] = f2bfbits(f3.z); t1[7] = f2bfbits(f3.w);
      a0 = __builtin_bit_cast(bf16x8, t0);
      a1 = __builtin_bit_cast(bf16x8, t1);
    }
  };
  auto write_tile = [&](bf16x8 a0, bf16x8 a1) {
    *(bf16x8*)(&kls[skv * KSTR + wid * 8]) = a0;
    *(bf16x8*)(&kls[skv * KSTR + (wid + 8) * 8]) = a1;
    #pragma unroll
    for (int j = 0; j < 8; ++j) {
      vls[(wid * 8 + j) * VSTR + skv] = a0[j];       // contiguous across lanes
      vls[((wid + 8) * 8 + j) * VSTR + skv] = a1[j];
    }
  };

  const f32x4 zero4 = {0.f, 0.f, 0.f, 0.f};
  f32x4 o[8];
  #pragma unroll
  for (int t = 0; t < 8; ++t) o[t] = zero4;
  float m[4], l[4];
  #pragma unroll
  for (int r = 0; r < 4; ++r) { m[r] = -1e30f; l[r] = 0.0f; }

  float* __restrict__ dotb = dot + ((size_t)(b * HH + h) << 22);  // S*S = 2^22

  // Prologue: stage tile 0
  bf16x8 p0, p1;
  load_tile(0, p0, p1);
  write_tile(p0, p1);
  __syncthreads();

  for (int kt = 0; kt < NT; ++kt) {
    const int kvbase = kt * KBLK;

    // ---- QK^T: 16 MFMA; s[ct] holds rows 4g+r, cols ct*16+c ----
    f32x4 s[4];
    #pragma unroll
    for (int ct = 0; ct < 4; ++ct) s[ct] = zero4;
    __builtin_amdgcn_s_setprio(1);
    #pragma unroll
    for (int st = 0; st < 4; ++st) {
      #pragma unroll
      for (int ct = 0; ct < 4; ++ct) {
        bf16x8 bk = *(const bf16x8*)(&kls[(ct * 16 + c) * KSTR + st * 32 + 8 * g]);
        s[ct] = __builtin_amdgcn_mfma_f32_16x16x32_bf16(aq[st], bk, s[ct], 0, 0, 0);
      }
    }
    __builtin_amdgcn_s_setprio(0);

    // ---- T14: issue next tile's global loads; they complete under
    //      softmax + PV and get written to LDS after the barrier ----
    if (kt + 1 < NT) load_tile(kvbase + KBLK, p0, p1);

    // ---- scale + write raw scores to dot_prod (nontemporal: write-once) ----
    #pragma unroll
    for (int ct = 0; ct < 4; ++ct) s[ct] *= scale;
    #pragma unroll
    for (int r = 0; r < 4; ++r) {
      float* dp = dotb + (size_t)(qbase + wid * 16 + 4 * g + r) * SS + kvbase + c;
      #pragma unroll
      for (int ct = 0; ct < 4; ++ct)
        __builtin_nontemporal_store(s[ct][r], dp + ct * 16);
    }

    // ---- online softmax (row reduce across 16 lanes sharing g) ----
    float alpha[4];
    #pragma unroll
    for (int r = 0; r < 4; ++r) {
      float tm = fmaxf(fmaxf(s[0][r], s[1][r]), fmaxf(s[2][r], s[3][r]));
      #pragma unroll
      for (int off = 1; off < 16; off <<= 1) tm = fmaxf(tm, __shfl_xor(tm, off));
      float mn = fmaxf(m[r], tm);
      alpha[r] = __expf(m[r] - mn);
      m[r] = mn;
    }
    float rs[4] = {0.f, 0.f, 0.f, 0.f};
    #pragma unroll
    for (int ct = 0; ct < 4; ++ct) {
      #pragma unroll
      for (int r = 0; r < 4; ++r) {
        float p = __expf(s[ct][r] - m[r]);
        s[ct][r] = p;
        rs[r] += p;
      }
    }
    #pragma unroll
    for (int r = 0; r < 4; ++r) {
      #pragma unroll
      for (int off = 1; off < 16; off <<= 1) rs[r] += __shfl_xor(rs[r], off);
      l[r] = l[r] * alpha[r] + rs[r];
      #pragma unroll
      for (int t = 0; t < 8; ++t) o[t][r] *= alpha[r];
    }

    // ---- P -> per-wave LDS (private region; same-wave read, no barrier) ----
    {
      __bf16* pw = &pls[wid * 16 * PSTR];
      #pragma unroll
      for (int ct = 0; ct < 4; ++ct)
        #pragma unroll
        for (int r = 0; r < 4; ++r)
          pw[(4 * g + r) * PSTR + ct * 16 + c] = f2bf(s[ct][r]);
    }

    // ---- PV: 16 MFMA, accumulate O[8 dph-tiles] ----
    __builtin_amdgcn_s_setprio(1);
    #pragma unroll
    for (int kk = 0; kk < 2; ++kk) {
      bf16x8 ap = *(const bf16x8*)(&pls[(wid * 16 + c) * PSTR + kk * 32 + 8 * g]);
      #pragma unroll
      for (int t = 0; t < 8; ++t) {
        bf16x8 bv = *(const bf16x8*)(&vls[(t * 16 + c) * VSTR + kk * 32 + 8 * g]);
        o[t] = __builtin_amdgcn_mfma_f32_16x16x32_bf16(ap, bv, o[t], 0, 0, 0);
      }
    }
    __builtin_amdgcn_s_setprio(0);

    __syncthreads();                       // all waves done reading kls/vls
    if (kt + 1 < NT) write_tile(p0, p1);   // stage tile kt+1
    __syncthreads();
  }

  // ---- epilogue: normalize and store out[b][q][h*128+d] ----
  #pragma unroll
  for (int r = 0; r < 4; ++r) {
    float inv = 1.0f / l[r];
    float* op = out + (size_t)(b * SS + qbase + wid * 16 + 4 * g + r) * DD + h * DPH_ + c;
    #pragma unroll
    for (int t = 0; t < 8; ++t)
      __builtin_nontemporal_store(o[t][r] * inv, op + t * 16);
  }

  // ---- epilogue: exact-fp32 prev_key/prev_value for this block's rows ----
  // Block (qt,h,b) owns q-rows [qbase, qbase+QBLK) of head h; pk/pv layout
  // [B,H,S,DPH]. 32 lanes x float4 = one 512B row per lane-group.
  {
    const size_t bh = (size_t)b * HH + h;
    const int col = (tid & 31) * 4;
    #pragma unroll
    for (int rr = 0; rr < QBLK; rr += 16) {
      const int row = qbase + rr + (tid >> 5);
      const float4 v = *(const float4*)(qfh + (size_t)row * DD + col);
      nt_store4(v, pk + (bh * SS + row) * DPH_ + col);
      nt_store4(v, pv + (bh * SS + row) * DPH_ + col);
    }
  }
}

extern "C" void kernel_launch(void* const* d_in, const int* in_sizes, int n_in,
                              void* d_out, int out_size, void* d_ws, size_t ws_size,
                              hipStream_t stream) {
  const float* q    = (const float*)d_in[0];
  const int*   mask = (const int*)d_in[1];
  float* out = (float*)d_out;

  // Output layout (concatenated flat, fp32):
  float* o_out  = out;                 // [B,S,D]        8,388,608
  float* o_pk   = out + 8388608;       // [B,H,S,DPH]    8,388,608
  float* o_pv   = out + 16777216;      // [B,H,S,DPH]    8,388,608
  float* o_mask = out + 25165824;      // [B,S]              4,096
  float* o_dot  = out + 25169920;      // [B*H,S,S]    134,217,728

  const size_t need = (size_t)BB * SS * DD * sizeof(__bf16);  // 16.8 MB
  const dim3 agrid(512);  // flat, XCD-swizzled in-kernel (16 qt x 16 h x 2 b)

  if (ws_size >= need) {
    __bf16* qbf = (__bf16*)d_ws;
    preproc<true><<<4096, 256, 0, stream>>>(q, mask, qbf, o_mask);
    attn_fused<true><<<agrid, 512, 0, stream>>>(qbf, q, o_out, o_dot, o_pk, o_pv);
  } else {
    preproc<false><<<4096, 256, 0, stream>>>(q, mask, nullptr, o_mask);
    attn_fused<false><<<agrid, 512, 0, stream>>>(nullptr, q, o_out, o_dot, o_pk, o_pv);
  }
}